// Round 6
// baseline (224.245 us; speedup 1.0000x reference)
//
#include <hip/hip_runtime.h>

#define BATCH 32
#define NROWS 8192
#define IND   128
#define HC    128
#define NEG   0.2f
#define NBLK  128                         // blocks per batch
#define ROWS  32                          // rows per iteration per block
#define ITERS 2                           // rows per block = 64
#define PART_STRIDE 136                   // 4 M + 4 S + 128 P floats

typedef __attribute__((ext_vector_type(8))) short short8;
typedef __attribute__((ext_vector_type(4))) float f32x4;

// lgkm-only barrier: orders LDS, leaves global loads/stores in flight
#define BARRIER() asm volatile("s_waitcnt lgkmcnt(0)\n\ts_barrier" ::: "memory")

__device__ __forceinline__ unsigned short f2bf(float f) {
    unsigned u = __float_as_uint(f);
    u += 0x7FFFu + ((u >> 16) & 1u);      // round-to-nearest-even
    return (unsigned short)(u >> 16);
}
__device__ __forceinline__ unsigned pack2(float a, float b) {
    return (unsigned)f2bf(a) | ((unsigned)f2bf(b) << 16);
}

// ---------------- kernel A: x_l for center rows only (B rows) ----------------
__global__ void gat_center(const float* __restrict__ x, const float* __restrict__ Wl,
                           const float* __restrict__ bl, float* __restrict__ xl0)
{
    const int b = blockIdx.x, t = threadIdx.x;   // 128 threads
    __shared__ float xrow[128];
    xrow[t] = x[(size_t)b * NROWS * IND + t];
    __syncthreads();
    float acc = bl[t];
#pragma unroll 16
    for (int k = 0; k < 128; ++k) acc = fmaf(xrow[k], Wl[k * 128 + t], acc);
    xl0[b * 128 + t] = acc;
}

// ---------------- kernel B: x_r GEMM + logits + online-softmax partials ------
// Small tiles (32 rows), many independent blocks (4096) for natural phase
// staggering across CUs.  W_r fragments from global (L2-hot); x tile via
// reg-prefetch -> bf16 swizzled LDS; epilogue via padded xr_s with contiguous
// float4 out-stores (the only store pattern with clean HBM traffic).
__global__ __launch_bounds__(256, 6) void gat_main(
    const float* __restrict__ x, const float* __restrict__ Wr,
    const float* __restrict__ br, const float* __restrict__ att,
    const float* __restrict__ xl0, float* __restrict__ out,
    float* __restrict__ part)
{
    const int tid  = threadIdx.x;
    const int lane = tid & 63;
    const int wv   = tid >> 6;
    const int b    = blockIdx.x >> 7;          // NBLK = 128
    const int blk  = blockIdx.x & (NBLK - 1);

    __shared__ float ubuf[ROWS * 132];         // union: x bf16 (8KB) / xr f32 (16.9KB)
    __shared__ float wmax_s[2][4], wsum_s[2][4];
    __shared__ float ptmp_s[2][128];
    __shared__ float xl0_s[128], att_s[128];

    unsigned short* Asw = (unsigned short*)ubuf;
    float (*xr_s)[132]  = (float(*)[132])ubuf;

    // per-thread x-tile chunk mapping (2 chunks of 8 floats; 512 chunks total)
    const int pr0 = tid >> 4, pr1 = (tid + 256) >> 4;   // rows 0..31
    const int pk  = (tid & 15) << 3;
    const size_t xorg = ((size_t)b * NROWS + (size_t)blk * (ITERS * ROWS)) * IND;

    float4 pf[2][2];                            // prefetched x chunk (16 VGPRs)
    {   // issue x loads FIRST (HBM latency) — overlap Wr/param loads below
        const float* s0 = x + xorg;
        pf[0][0] = *(const float4*)(s0 + pr0 * IND + pk);
        pf[0][1] = *(const float4*)(s0 + pr0 * IND + pk + 4);
        pf[1][0] = *(const float4*)(s0 + pr1 * IND + pk);
        pf[1][1] = *(const float4*)(s0 + pr1 * IND + pk + 4);
    }

    // ---- W_r fragments straight from global (L2-hot): wave wv owns cols wv*32..+31
    short8 bfr[2][4];
    {
        const int ksel = lane >> 4;
#pragma unroll
        for (int ct = 0; ct < 2; ++ct) {
            const int n = wv * 32 + ct * 16 + (lane & 15);
#pragma unroll
            for (int ks = 0; ks < 4; ++ks) {
                const int k0 = ks * 32 + ksel * 8;
                const float* wp = Wr + (size_t)k0 * HC + n;
                float v0 = wp[0 * HC], v1 = wp[1 * HC], v2 = wp[2 * HC], v3 = wp[3 * HC];
                float v4 = wp[4 * HC], v5 = wp[5 * HC], v6 = wp[6 * HC], v7 = wp[7 * HC];
                union { short8 s; unsigned u[4]; } t;
                t.u[0] = pack2(v0, v1); t.u[1] = pack2(v2, v3);
                t.u[2] = pack2(v4, v5); t.u[3] = pack2(v6, v7);
                bfr[ct][ks] = t.s;
            }
        }
    }
    if (tid < 128) { xl0_s[tid] = xl0[b * 128 + tid]; att_s[tid] = att[tid]; }
    // per-thread spill cols and bias
    const int   c0 = wv * 32 + (lane & 15), c1 = c0 + 16;
    const float bi0 = br[c0], bi1 = br[c1];

    const int lh = tid & 3;                     // logits mapping (tid<128): row tid>>2, head lh
    const int hcp = tid & 127, half = tid >> 7; // P mapping: col hcp, row-half
    const int hp  = hcp >> 5;                   // P thread's head

    float Mrun = -INFINITY, Srun = 0.f, Prun = 0.f;

    for (int it = 0; it < ITERS; ++it) {
        // ---- stage prefetched chunks -> bf16 swizzled LDS (pf dies)
        {
            uint4 u0, u1;
            u0.x = pack2(pf[0][0].x, pf[0][0].y); u0.y = pack2(pf[0][0].z, pf[0][0].w);
            u0.z = pack2(pf[0][1].x, pf[0][1].y); u0.w = pack2(pf[0][1].z, pf[0][1].w);
            u1.x = pack2(pf[1][0].x, pf[1][0].y); u1.y = pack2(pf[1][0].z, pf[1][0].w);
            u1.z = pack2(pf[1][1].x, pf[1][1].y); u1.w = pack2(pf[1][1].z, pf[1][1].w);
            *(uint4*)&Asw[pr0 * 128 + (pk ^ ((pr0 & 7) << 3))] = u0;
            *(uint4*)&Asw[pr1 * 128 + (pk ^ ((pr1 & 7) << 3))] = u1;
        }
        BARRIER();

        // ---- MFMA: 32 rows x this wave's 32 cols, K=128
        f32x4 acc[2][2];
#pragma unroll
        for (int i = 0; i < 2; ++i)
#pragma unroll
            for (int j = 0; j < 2; ++j) acc[i][j] = (f32x4){0.f, 0.f, 0.f, 0.f};
        {
            const int ksel = lane >> 4;
#pragma unroll
            for (int rt = 0; rt < 2; ++rt) {
                const int rA  = rt * 16 + (lane & 15);
                const int swa = (rA & 7) << 3;
                short8 afr[4];
#pragma unroll
                for (int ks = 0; ks < 4; ++ks) {
                    int k0 = ks * 32 + ksel * 8;
                    afr[ks] = *(const short8*)&Asw[rA * 128 + (k0 ^ swa)];
                }
#pragma unroll
                for (int ct = 0; ct < 2; ++ct)
#pragma unroll
                    for (int ks = 0; ks < 4; ++ks)
                        acc[rt][ct] = __builtin_amdgcn_mfma_f32_16x16x32_bf16(
                            afr[ks], bfr[ct][ks], acc[rt][ct], 0, 0, 0);
            }
        }
        BARRIER();   // Asw reads done before union becomes xr_s

        // ---- spill acc -> xr_s with bias (2-way banks; acc dies)
        {
            const int rq = (lane >> 4) * 4;
#pragma unroll
            for (int rt = 0; rt < 2; ++rt)
#pragma unroll
                for (int rg = 0; rg < 4; ++rg) {
                    xr_s[rt * 16 + rq + rg][c0] = acc[rt][0][rg] + bi0;
                    xr_s[rt * 16 + rq + rg][c1] = acc[rt][1][rg] + bi1;
                }
        }
        BARRIER();

        // ---- prefetch next tile now (acc dead; in flight through epilogue)
        if (it + 1 < ITERS) {
            const float* s1 = x + xorg + (size_t)(it + 1) * ROWS * IND;
            pf[0][0] = *(const float4*)(s1 + pr0 * IND + pk);
            pf[0][1] = *(const float4*)(s1 + pr0 * IND + pk + 4);
            pf[1][0] = *(const float4*)(s1 + pr1 * IND + pk);
            pf[1][1] = *(const float4*)(s1 + pr1 * IND + pk + 4);
        }

        // ---- contiguous float4 out-stores (1 KB per wave per pass)
        {
            float* ob = out + ((size_t)b * NROWS + (size_t)blk * (ITERS * ROWS) + it * ROWS) * HC;
#pragma unroll
            for (int j = 0; j < 4; ++j) {
                int idx = tid + j * 256;
                int row = idx >> 5, cc = (idx & 31) << 2;
                *(float4*)(ob + row * HC + cc) = *(const float4*)&xr_s[row][cc];
            }
        }

        // ---- logits (tid<128): row tid>>2, head lh; dot over 32 cols
        float lg = 0.f, w = 0.f;
        if (tid < 128) {
            const int lr = tid >> 2;
            const float* xp = &xr_s[lr][lh * 32];
            const float* ap = &att_s[lh * 32];
            const float* qp = &xl0_s[lh * 32];
#pragma unroll
            for (int c4 = 0; c4 < 32; c4 += 4) {
                float4 xv = *(const float4*)(xp + c4);
                float4 av = *(const float4*)(ap + c4);
                float4 qv = *(const float4*)(qp + c4);
                float v0 = qv.x + xv.x; v0 = v0 > 0.f ? v0 : NEG * v0;
                float v1 = qv.y + xv.y; v1 = v1 > 0.f ? v1 : NEG * v1;
                float v2 = qv.z + xv.z; v2 = v2 > 0.f ? v2 : NEG * v2;
                float v3 = qv.w + xv.w; v3 = v3 > 0.f ? v3 : NEG * v3;
                lg = fmaf(v0, av.x, fmaf(v1, av.y, fmaf(v2, av.z, fmaf(v3, av.w, lg))));
            }
            float mx = lg;
#pragma unroll
            for (int mk = 4; mk < 64; mk <<= 1) mx = fmaxf(mx, __shfl_xor(mx, mk));
            if (lane < 4) wmax_s[wv][lane] = mx;   // wv in {0,1}
        }
        BARRIER();

        // block max for this iter, per head (everyone reads)
        if (tid < 128) {
            const float Mb   = fmaxf(wmax_s[0][lh], wmax_s[1][lh]);
            const float Mnew = fmaxf(Mrun, Mb);
            w = __expf(lg - Mnew);
            float swv = w;
#pragma unroll
            for (int mk = 4; mk < 64; mk <<= 1) swv += __shfl_xor(swv, mk);
            if (lane < 4) wsum_s[wv][lane] = swv;
            // stash w for the P phase via xr_s? no — w is consumed below from
            // registers only by logits threads; P threads need it, so use LDS:
            ptmp_s[0][tid] = w;                    // ptmp_s[0] = w for row tid>>2, head lh
        }
        BARRIER();

        // ---- all threads: update running M/S (registers, redundant per head)
        {
            const float Mb   = fmaxf(wmax_s[0][hp], wmax_s[1][hp]);
            const float Mnew = fmaxf(Mrun, Mb);
            const float sc   = __expf(Mrun - Mnew);
            Srun = Srun * sc + (wsum_s[0][hp] + wsum_s[1][hp]);
            // P partial: rows half*16 .. +15, col hcp
            float accp = 0.f;
#pragma unroll
            for (int i2 = 0; i2 < 16; ++i2) {
                const int rr = half * 16 + i2;
                accp = fmaf(ptmp_s[0][rr * 4 + hp], xr_s[rr][hcp], accp);
            }
            Prun = Prun * sc + accp;
            Mrun = Mnew;
        }
        BARRIER();   // xr_s / ptmp_s reads done before next stage / reuse
    }

    // ---- write block partials
    ptmp_s[half][hcp] = Prun;
    BARRIER();
    float* pb = part + (size_t)(b * NBLK + blk) * PART_STRIDE;
    if (tid < 128) {
        if ((hcp & 31) == 0) { pb[hp] = Mrun; pb[4 + hp] = Srun; }
        pb[8 + hcp] = ptmp_s[0][hcp] + ptmp_s[1][hcp];
    }
}

// ---------------- kernel C: combine partials, write center row ---------------
__global__ void gat_final(const float* __restrict__ part, float* __restrict__ out)
{
    const int b = blockIdx.x, t = threadIdx.x;   // 128 threads: t = h*32+c
    const int h = t >> 5;
    const float* pb = part + (size_t)b * NBLK * PART_STRIDE;
    float Mg = -INFINITY;
#pragma unroll 4
    for (int i = 0; i < NBLK; ++i) Mg = fmaxf(Mg, pb[i * PART_STRIDE + h]);
    float Sg = 0.f, Pg = 0.f;
#pragma unroll 4
    for (int i = 0; i < NBLK; ++i) {
        const float sc = __expf(pb[i * PART_STRIDE + h] - Mg);
        Sg += pb[i * PART_STRIDE + 4 + h] * sc;
        Pg  = fmaf(pb[i * PART_STRIDE + 8 + t], sc, Pg);
    }
    out[(size_t)b * NROWS * HC + t] = Pg / Sg;
}

extern "C" void kernel_launch(void* const* d_in, const int* in_sizes, int n_in,
                              void* d_out, int out_size, void* d_ws, size_t ws_size,
                              hipStream_t stream)
{
    const float* x   = (const float*)d_in[0];
    const float* Wl  = (const float*)d_in[1];
    const float* bl  = (const float*)d_in[2];
    const float* Wr  = (const float*)d_in[3];
    const float* br  = (const float*)d_in[4];
    const float* att = (const float*)d_in[5];
    float* out = (float*)d_out;

    float* xl0  = (float*)d_ws;                // 32*128 f32
    float* part = xl0 + BATCH * 128;           // 32*128*136 f32 = 2.23 MB

    gat_center<<<BATCH, 128, 0, stream>>>(x, Wl, bl, xl0);
    gat_main<<<BATCH * NBLK, 256, 0, stream>>>(x, Wr, br, att, xl0, out, part);
    gat_final<<<BATCH, 128, 0, stream>>>(part, out);
}

// Round 7
// 119.107 us; speedup vs baseline: 1.8827x; 1.8827x over previous
//
#include <hip/hip_runtime.h>

#define BATCH 32
#define NROWS 8192
#define IND   128
#define HC    128
#define NEG   0.2f
#define TILES 8                           // row-tiles per wave
#define TROWS 16                          // rows per tile (one MFMA row block)
#define WPB   64                          // wave-units per batch = 8192/(16*8)
#define PART_STRIDE 136                   // 4 M + 4 S + 128 P floats

typedef __attribute__((ext_vector_type(8))) short short8;
typedef __attribute__((ext_vector_type(4))) float f32x4;

// compiler-only fence: keeps source order of LDS ops (cross-lane exchange in a
// wave-private slab needs program order; DS pipe executes a wave's ops in order)
#define CFENCE() asm volatile("" ::: "memory")

__device__ __forceinline__ unsigned short f2bf(float f) {
    unsigned u = __float_as_uint(f);
    u += 0x7FFFu + ((u >> 16) & 1u);      // round-to-nearest-even
    return (unsigned short)(u >> 16);
}
__device__ __forceinline__ unsigned pack2(float a, float b) {
    return (unsigned)f2bf(a) | ((unsigned)f2bf(b) << 16);
}

// ---------------- kernel A: x_l for center rows only (B rows) ----------------
__global__ void gat_center(const float* __restrict__ x, const float* __restrict__ Wl,
                           const float* __restrict__ bl, float* __restrict__ xl0)
{
    const int b = blockIdx.x, t = threadIdx.x;   // 128 threads
    __shared__ float xrow[128];
    xrow[t] = x[(size_t)b * NROWS * IND + t];
    __syncthreads();
    float acc = bl[t];
#pragma unroll 16
    for (int k = 0; k < 128; ++k) acc = fmaf(xrow[k], Wl[k * 128 + t], acc);
    xl0[b * 128 + t] = acc;
}

// ---------------- kernel B: barrier-free per-wave GEMM + fused epilogue ------
// Each wave independently owns 16-row tiles x all 128 cols.  W_r^T lives in
// registers (128 VGPRs, same in every wave).  A-fragments load straight from
// global (x read once).  Epilogue (out-store transpose, logits, online
// softmax, P partial) is wave-private: own LDS slab + shuffles.  ZERO
// workgroup barriers in the loop.
__global__ __launch_bounds__(256, 2) void gat_main(
    const float* __restrict__ x, const float* __restrict__ Wr,
    const float* __restrict__ br, const float* __restrict__ att,
    const float* __restrict__ xl0, float* __restrict__ out,
    float* __restrict__ part)
{
    const int tid  = threadIdx.x;
    const int lane = tid & 63;
    const int wv   = tid >> 6;
    const int b    = blockIdx.x >> 4;          // 16 blocks per batch
    const int wu   = (blockIdx.x & 15) * 4 + wv;

    __shared__ float lds[4 * 2176 + 256];      // 35 KB
    float* xr_s  = lds + wv * 2176;            // wave-private [16][132] f32
    float* w_s   = xr_s + 2112;                // wave-private [4][16]
    float* att_s = lds + 4 * 2176;             // block const [128]
    float* xl0_s = att_s + 128;                // block const [128]

    if (tid < 128) { att_s[tid] = att[tid]; xl0_s[tid] = xl0[b * 128 + tid]; }

    const int l15 = lane & 15, ksel = lane >> 4;

    // ---- W_r^T fragments -> registers (one-time, strided scalar reads, L2-hot)
    short8 bfr[8][4];
#pragma unroll
    for (int nt = 0; nt < 8; ++nt) {
        const int n = nt * 16 + l15;
#pragma unroll
        for (int ks = 0; ks < 4; ++ks) {
            const float* wp = Wr + (size_t)(ks * 32 + ksel * 8) * HC + n;
            float v0 = wp[0 * HC], v1 = wp[1 * HC], v2 = wp[2 * HC], v3 = wp[3 * HC];
            float v4 = wp[4 * HC], v5 = wp[5 * HC], v6 = wp[6 * HC], v7 = wp[7 * HC];
            union { short8 s; unsigned u[4]; } u;
            u.u[0] = pack2(v0, v1); u.u[1] = pack2(v2, v3);
            u.u[2] = pack2(v4, v5); u.u[3] = pack2(v6, v7);
            bfr[nt][ks] = u.s;
        }
    }
    float bi[8];
#pragma unroll
    for (int nt = 0; nt < 8; ++nt) bi[nt] = br[nt * 16 + l15];

    __syncthreads();   // const slab ready (only barrier in the kernel)

    const size_t row0 = (size_t)b * NROWS + (size_t)wu * (TILES * TROWS);
    const int lr = lane >> 2, lh = lane & 3;       // logits mapping: row, head
    const int pc0 = lane, pc1 = lane + 64;         // P cols
    const int h0 = pc0 >> 5, h1 = 2 + (pc0 >> 5);  // their heads

    // ---- prologue: load + pack tile-0 A fragments
    short8 afr[4];
    {
        const float* sp = x + (row0 + l15) * IND;
        float4 pf0[4][2];
#pragma unroll
        for (int ks = 0; ks < 4; ++ks) {
            pf0[ks][0] = *(const float4*)(sp + ks * 32 + ksel * 8);
            pf0[ks][1] = *(const float4*)(sp + ks * 32 + ksel * 8 + 4);
        }
#pragma unroll
        for (int ks = 0; ks < 4; ++ks) {
            union { short8 s; unsigned u[4]; } u;
            u.u[0] = pack2(pf0[ks][0].x, pf0[ks][0].y);
            u.u[1] = pack2(pf0[ks][0].z, pf0[ks][0].w);
            u.u[2] = pack2(pf0[ks][1].x, pf0[ks][1].y);
            u.u[3] = pack2(pf0[ks][1].z, pf0[ks][1].w);
            afr[ks] = u.s;
        }
    }

    float Mrun = -INFINITY, Srun = 0.f, P0 = 0.f, P1 = 0.f;

    for (int t = 0; t < TILES; ++t) {
        // 1. MFMA: 16 rows x 128 cols, K=128
        f32x4 acc[8];
#pragma unroll
        for (int nt = 0; nt < 8; ++nt) acc[nt] = (f32x4){0.f, 0.f, 0.f, 0.f};
#pragma unroll
        for (int nt = 0; nt < 8; ++nt)
#pragma unroll
            for (int ks = 0; ks < 4; ++ks)
                acc[nt] = __builtin_amdgcn_mfma_f32_16x16x32_bf16(
                    afr[ks], bfr[nt][ks], acc[nt], 0, 0, 0);

        // 2. issue next tile's A loads — latency hides under the epilogue
        float4 pf[4][2];
        if (t + 1 < TILES) {
            const float* sp = x + (row0 + (size_t)(t + 1) * TROWS + l15) * IND;
#pragma unroll
            for (int ks = 0; ks < 4; ++ks) {
                pf[ks][0] = *(const float4*)(sp + ks * 32 + ksel * 8);
                pf[ks][1] = *(const float4*)(sp + ks * 32 + ksel * 8 + 4);
            }
        }

        // 3. spill acc -> wave-private xr_s (+bias); row = ksel*4+rg (2-way banks)
#pragma unroll
        for (int nt = 0; nt < 8; ++nt)
#pragma unroll
            for (int rg = 0; rg < 4; ++rg)
                xr_s[(ksel * 4 + rg) * 132 + nt * 16 + l15] = acc[nt][rg] + bi[nt];
        CFENCE();

        // 4. out stores: 8 instrs x 1 KB contiguous (rows 2j,2j+1)
        {
            float* ob = out + (row0 + (size_t)t * TROWS) * HC;
#pragma unroll
            for (int j = 0; j < 8; ++j) {
                const int row = 2 * j + (lane >> 5);
                const int cc  = (lane & 31) * 4;
                *(float4*)(ob + (size_t)row * HC + cc) =
                    *(const float4*)&xr_s[row * 132 + cc];
            }
        }

        // 5. logits: lane = (row lr, head lh); full 32-col dot in-lane
        float lg = 0.f;
        {
            const float* xp = &xr_s[lr * 132 + lh * 32];
            const float* ap = &att_s[lh * 32];
            const float* qp = &xl0_s[lh * 32];
#pragma unroll
            for (int c4 = 0; c4 < 32; c4 += 4) {
                float4 xv = *(const float4*)(xp + c4);
                float4 av = *(const float4*)(ap + c4);
                float4 qv = *(const float4*)(qp + c4);
                float v0 = qv.x + xv.x; v0 = v0 > 0.f ? v0 : NEG * v0;
                float v1 = qv.y + xv.y; v1 = v1 > 0.f ? v1 : NEG * v1;
                float v2 = qv.z + xv.z; v2 = v2 > 0.f ? v2 : NEG * v2;
                float v3 = qv.w + xv.w; v3 = v3 > 0.f ? v3 : NEG * v3;
                lg = fmaf(v0, av.x, fmaf(v1, av.y, fmaf(v2, av.z, fmaf(v3, av.w, lg))));
            }
        }
        // per-head max over the 16 rows (lanes with same lh)
        float mx = lg;
        mx = fmaxf(mx, __shfl_xor(mx, 4));
        mx = fmaxf(mx, __shfl_xor(mx, 8));
        mx = fmaxf(mx, __shfl_xor(mx, 16));
        mx = fmaxf(mx, __shfl_xor(mx, 32));
        const float Mnew = fmaxf(Mrun, mx);
        const float w    = __expf(lg - Mnew);
        float sw = w;
        sw += __shfl_xor(sw, 4);  sw += __shfl_xor(sw, 8);
        sw += __shfl_xor(sw, 16); sw += __shfl_xor(sw, 32);
        const float sc = __expf(Mrun - Mnew);      // 0 on first tile
        Srun = Srun * sc + sw;
        Mrun = Mnew;
        w_s[lh * 16 + lr] = w;
        CFENCE();

        // 6. P partial: lane owns cols pc0/pc1; w broadcast-read from w_s
        {
            const float sc0 = __shfl(sc, h0);      // lane h holds head h's sc
            const float sc1 = __shfl(sc, h1);
            const float* w0 = &w_s[h0 * 16];
            const float* w1 = &w_s[h1 * 16];
            float a0 = 0.f, a1 = 0.f;
#pragma unroll
            for (int r = 0; r < 16; ++r) {
                a0 = fmaf(w0[r], xr_s[r * 132 + pc0], a0);
                a1 = fmaf(w1[r], xr_s[r * 132 + pc1], a1);
            }
            P0 = P0 * sc0 + a0;
            P1 = P1 * sc1 + a1;
        }

        // 7. pack next tile's fragments (pf dies)
        if (t + 1 < TILES) {
#pragma unroll
            for (int ks = 0; ks < 4; ++ks) {
                union { short8 s; unsigned u[4]; } u;
                u.u[0] = pack2(pf[ks][0].x, pf[ks][0].y);
                u.u[1] = pack2(pf[ks][0].z, pf[ks][0].w);
                u.u[2] = pack2(pf[ks][1].x, pf[ks][1].y);
                u.u[3] = pack2(pf[ks][1].z, pf[ks][1].w);
                afr[ks] = u.s;
            }
        }
    }

    // ---- write wave partials
    float* pb = part + (size_t)(b * WPB + wu) * PART_STRIDE;
    if (lane < 4) { pb[lane] = Mrun; pb[4 + lane] = Srun; }  // lanes 0-3: lr=0, lh=lane
    pb[8 + pc0] = P0;
    pb[8 + pc1] = P1;
}

// ---------------- kernel C: combine partials, write center row ---------------
__global__ void gat_final(const float* __restrict__ part, float* __restrict__ out)
{
    const int b = blockIdx.x, t = threadIdx.x;   // 128 threads: t = h*32+c
    const int h = t >> 5;
    const float* pb = part + (size_t)b * WPB * PART_STRIDE;
    float Mg = -INFINITY;
#pragma unroll 4
    for (int i = 0; i < WPB; ++i) Mg = fmaxf(Mg, pb[i * PART_STRIDE + h]);
    float Sg = 0.f, Pg = 0.f;
#pragma unroll 4
    for (int i = 0; i < WPB; ++i) {
        const float sc = __expf(pb[i * PART_STRIDE + h] - Mg);
        Sg += pb[i * PART_STRIDE + 4 + h] * sc;
        Pg  = fmaf(pb[i * PART_STRIDE + 8 + t], sc, Pg);
    }
    out[(size_t)b * NROWS * HC + t] = Pg / Sg;
}

extern "C" void kernel_launch(void* const* d_in, const int* in_sizes, int n_in,
                              void* d_out, int out_size, void* d_ws, size_t ws_size,
                              hipStream_t stream)
{
    const float* x   = (const float*)d_in[0];
    const float* Wl  = (const float*)d_in[1];
    const float* bl  = (const float*)d_in[2];
    const float* Wr  = (const float*)d_in[3];
    const float* br  = (const float*)d_in[4];
    const float* att = (const float*)d_in[5];
    float* out = (float*)d_out;

    float* xl0  = (float*)d_ws;                // 32*128 f32
    float* part = xl0 + BATCH * 128;           // 32*64*136 f32 = 1.1 MB

    gat_center<<<BATCH, 128, 0, stream>>>(x, Wl, bl, xl0);
    gat_main<<<BATCH * 16, 256, 0, stream>>>(x, Wr, br, att, xl0, out, part);
    gat_final<<<BATCH, 128, 0, stream>>>(part, out);
}

// Round 8
// 95.033 us; speedup vs baseline: 2.3597x; 1.2533x over previous
//
#include <hip/hip_runtime.h>

#define BATCH 32
#define NROWS 8192
#define IND   128
#define HC    128
#define NEG   0.2f
#define NBLK  32                          // blocks per batch
#define ROWS  64                          // rows per iteration per block
#define ITERS 4
#define PART_STRIDE 136                   // 4 M + 4 S + 128 P floats

typedef __attribute__((ext_vector_type(8))) short short8;
typedef __attribute__((ext_vector_type(4))) float f32x4;

// lgkm-only barrier: orders LDS, leaves global loads/stores in flight
#define BARRIER() asm volatile("s_waitcnt lgkmcnt(0)\n\ts_barrier" ::: "memory")
#define CFENCE()  asm volatile("" ::: "memory")

__device__ __forceinline__ unsigned short f2bf(float f) {
    unsigned u = __float_as_uint(f);
    u += 0x7FFFu + ((u >> 16) & 1u);      // round-to-nearest-even
    return (unsigned short)(u >> 16);
}
__device__ __forceinline__ unsigned pack2(float a, float b) {
    return (unsigned)f2bf(a) | ((unsigned)f2bf(b) << 16);
}

// ---------------- kernel A: x_l for center rows only (B rows) ----------------
__global__ void gat_center(const float* __restrict__ x, const float* __restrict__ Wl,
                           const float* __restrict__ bl, float* __restrict__ xl0)
{
    const int b = blockIdx.x, t = threadIdx.x;   // 128 threads
    __shared__ float xrow[128];
    xrow[t] = x[(size_t)b * NROWS * IND + t];
    __syncthreads();
    float acc = bl[t];
#pragma unroll 16
    for (int k = 0; k < 128; ++k) acc = fmaf(xrow[k], Wl[k * 128 + t], acc);
    xl0[b * 128 + t] = acc;
}

// ---------------- kernel B: 2-barrier GEMM + wave-private fused epilogue -----
// Wave wv owns 64 rows x cols [wv*32, wv*32+32) == head wv.  Logits, online
// softmax and P-partials are computed entirely from acc in registers via
// shuffles (no cross-wave traffic).  Out-store goes through a wave-private
// LDS slab to produce contiguous 128B-segment float4 stores.  Exactly two
// workgroup barriers per iteration (stage->MFMA, MFMA->next stage).
__global__ __launch_bounds__(256, 3) void gat_main(
    const float* __restrict__ x, const float* __restrict__ Wr,
    const float* __restrict__ br, const float* __restrict__ att,
    const float* __restrict__ xl0, float* __restrict__ out,
    float* __restrict__ part)
{
    const int tid  = threadIdx.x;
    const int lane = tid & 63;
    const int wv   = tid >> 6;
    const int b    = blockIdx.x >> 5;          // NBLK = 32
    const int blk  = blockIdx.x & (NBLK - 1);
    const int l15  = lane & 15, ksel = lane >> 4;

    // LDS: [0,16KB) Asw bf16 64x128 | [16KB,49.8KB) 4 wave slabs [64][33] f32.
    // Prologue reuses [0,32KB) as WrT bf16 128x128.
    __shared__ float lds_pool[4096 + 4 * 2112];
    unsigned short* WrT  = (unsigned short*)lds_pool;
    unsigned short* Asw  = (unsigned short*)lds_pool;
    float*          slab = lds_pool + 4096 + wv * 2112;   // wave-private [64][33]

    // per-thread x-tile chunk mapping (4 chunks of 8 floats)
    const int pr[4] = { tid >> 4, (tid + 256) >> 4, (tid + 512) >> 4, (tid + 768) >> 4 };
    const int pk    = (tid & 15) << 3;
    const size_t xorg = ((size_t)b * NROWS + (size_t)blk * (ITERS * ROWS)) * IND;

    float4 pf[4][2];                            // prefetched x chunks (32 VGPRs)
    {   // tile-0 loads first (HBM latency hides under WrT staging)
        const float* s0 = x + xorg;
#pragma unroll
        for (int ii = 0; ii < 4; ++ii) {
            pf[ii][0] = *(const float4*)(s0 + pr[ii] * IND + pk);
            pf[ii][1] = *(const float4*)(s0 + pr[ii] * IND + pk + 4);
        }
    }

    // ---- prologue: WrT bf16 swizzled into LDS (coalesced), frags -> regs
    for (int i = tid; i < 128 * 128; i += 256) {
        int n = i & 127, k = i >> 7;
        WrT[n * 128 + (k ^ ((n & 7) << 3))] = f2bf(Wr[k * 128 + n]);
    }
    BARRIER();
    short8 bfr[2][4];
#pragma unroll
    for (int ct = 0; ct < 2; ++ct) {
        const int n  = wv * 32 + ct * 16 + l15;
        const int sw = (n & 7) << 3;
#pragma unroll
        for (int ks = 0; ks < 4; ++ks)
            bfr[ct][ks] = *(const short8*)&WrT[n * 128 + ((ks * 32 + ksel * 8) ^ sw)];
    }
    BARRIER();   // WrT reads done before lds_pool is reused (Asw + slabs)

    // per-lane head-wv parameters (cols c0/c1 of head wv)
    const int   c0 = wv * 32 + l15, c1 = c0 + 16;
    const float q0 = xl0[b * 128 + c0], q1 = xl0[b * 128 + c1];
    const float a0 = att[c0],           a1 = att[c1];
    const float bi0 = br[c0],           bi1 = br[c1];

    float Mrun = -INFINITY, Srun = 0.f, P0 = 0.f, P1 = 0.f;

    for (int t = 0; t < ITERS; ++t) {
        // ---- stage prefetched tile -> bf16 swizzled Asw (pf dies)
#pragma unroll
        for (int ii = 0; ii < 4; ++ii) {
            uint4 u;
            u.x = pack2(pf[ii][0].x, pf[ii][0].y); u.y = pack2(pf[ii][0].z, pf[ii][0].w);
            u.z = pack2(pf[ii][1].x, pf[ii][1].y); u.w = pack2(pf[ii][1].z, pf[ii][1].w);
            *(uint4*)&Asw[pr[ii] * 128 + (pk ^ ((pr[ii] & 7) << 3))] = u;
        }
        BARRIER();                         // B1: tile staged

        // ---- MFMA: 64 rows x this wave's 32 cols, K=128
        f32x4 acc[4][2];
#pragma unroll
        for (int i = 0; i < 4; ++i)
#pragma unroll
            for (int j = 0; j < 2; ++j) acc[i][j] = (f32x4){0.f, 0.f, 0.f, 0.f};
#pragma unroll
        for (int rt = 0; rt < 4; ++rt) {
            const int rA  = rt * 16 + l15;
            const int swa = (rA & 7) << 3;
            short8 afr[4];
#pragma unroll
            for (int ks = 0; ks < 4; ++ks)
                afr[ks] = *(const short8*)&Asw[rA * 128 + ((ks * 32 + ksel * 8) ^ swa)];
#pragma unroll
            for (int ct = 0; ct < 2; ++ct)
#pragma unroll
                for (int ks = 0; ks < 4; ++ks)
                    acc[rt][ct] = __builtin_amdgcn_mfma_f32_16x16x32_bf16(
                        afr[ks], bfr[ct][ks], acc[rt][ct], 0, 0, 0);
        }

        // ---- next tile's loads in flight through B2 + epilogue
        if (t + 1 < ITERS) {
            const float* s1 = x + xorg + (size_t)(t + 1) * ROWS * IND;
#pragma unroll
            for (int ii = 0; ii < 4; ++ii) {
                pf[ii][0] = *(const float4*)(s1 + pr[ii] * IND + pk);
                pf[ii][1] = *(const float4*)(s1 + pr[ii] * IND + pk + 4);
            }
        }
        BARRIER();                         // B2: all Asw reads done

        // ---- bias in place + spill to wave-private slab (D layout:
        //      row = rt*16 + ksel*4 + rg, col(acc[..][ct]) = ct*16 + l15)
#pragma unroll
        for (int rt = 0; rt < 4; ++rt)
#pragma unroll
            for (int rg = 0; rg < 4; ++rg) {
                const int row = rt * 16 + ksel * 4 + rg;
                float v0 = acc[rt][0][rg] + bi0; acc[rt][0][rg] = v0;
                float v1 = acc[rt][1][rg] + bi1; acc[rt][1][rg] = v1;
                slab[row * 33 + l15]      = v0;
                slab[row * 33 + 16 + l15] = v1;
            }
        CFENCE();

        // ---- out store: wave's 128B column band, contiguous float4
        {
            float* ob = out + ((size_t)b * NROWS + (size_t)blk * (ITERS * ROWS)
                               + (size_t)t * ROWS) * HC + wv * 32;
            const int sr = lane >> 3, scl = (lane & 7) * 4;
#pragma unroll
            for (int j = 0; j < 8; ++j) {
                const int row = j * 8 + sr;
                *(float4*)(ob + (size_t)row * HC + scl) =
                    *(const float4*)&slab[row * 33 + scl];
            }
        }

        // ---- logits for head wv (all in registers)
        float s[4][4];
#pragma unroll
        for (int rt = 0; rt < 4; ++rt)
#pragma unroll
            for (int rg = 0; rg < 4; ++rg) {
                float v0 = q0 + acc[rt][0][rg]; v0 = v0 > 0.f ? v0 : NEG * v0;
                float v1 = q1 + acc[rt][1][rg]; v1 = v1 > 0.f ? v1 : NEG * v1;
                s[rt][rg] = fmaf(v0, a0, v1 * a1);
            }
#pragma unroll
        for (int mk = 1; mk < 16; mk <<= 1)
#pragma unroll
            for (int rt = 0; rt < 4; ++rt)
#pragma unroll
                for (int rg = 0; rg < 4; ++rg)
                    s[rt][rg] += __shfl_xor(s[rt][rg], mk);
        // lane now holds full logits for rows rt*16+ksel*4+rg (replicated over l15)

        // ---- online softmax + P partial (registers + 2 shuffles per reduce)
        float mx = s[0][0];
#pragma unroll
        for (int rt = 0; rt < 4; ++rt)
#pragma unroll
            for (int rg = 0; rg < 4; ++rg) mx = fmaxf(mx, s[rt][rg]);
        mx = fmaxf(mx, __shfl_xor(mx, 16));
        mx = fmaxf(mx, __shfl_xor(mx, 32));
        const float Mnew = fmaxf(Mrun, mx);
        const float sc   = __expf(Mrun - Mnew);     // 0 on first tile
        float sw = 0.f, p0 = 0.f, p1 = 0.f;
#pragma unroll
        for (int rt = 0; rt < 4; ++rt)
#pragma unroll
            for (int rg = 0; rg < 4; ++rg) {
                const float w = __expf(s[rt][rg] - Mnew);
                sw += w;
                p0 = fmaf(w, acc[rt][0][rg], p0);
                p1 = fmaf(w, acc[rt][1][rg], p1);
            }
        sw += __shfl_xor(sw, 16); sw += __shfl_xor(sw, 32);
        p0 += __shfl_xor(p0, 16); p0 += __shfl_xor(p0, 32);
        p1 += __shfl_xor(p1, 16); p1 += __shfl_xor(p1, 32);
        Srun = Srun * sc + sw;
        P0   = P0 * sc + p0;
        P1   = P1 * sc + p1;
        Mrun = Mnew;
        // no barrier: next stage writes Asw; all Asw reads finished before B2.
        // slab is wave-private (same-wave DS ordering).
    }

    // ---- write block partials (head wv)
    float* pb = part + (size_t)(b * NBLK + blk) * PART_STRIDE;
    if (lane == 0) { pb[wv] = Mrun; pb[4 + wv] = Srun; }
    if (ksel == 0) { pb[8 + c0] = P0; pb[8 + c1] = P1; }
}

// ---------------- kernel C: combine partials, write center row ---------------
__global__ void gat_final(const float* __restrict__ part, float* __restrict__ out)
{
    const int b = blockIdx.x, t = threadIdx.x;   // 128 threads: t = h*32+c
    const int h = t >> 5;
    const float* pb = part + (size_t)b * NBLK * PART_STRIDE;
    float Mg = -INFINITY;
#pragma unroll 4
    for (int i = 0; i < NBLK; ++i) Mg = fmaxf(Mg, pb[i * PART_STRIDE + h]);
    float Sg = 0.f, Pg = 0.f;
#pragma unroll 4
    for (int i = 0; i < NBLK; ++i) {
        const float sc = __expf(pb[i * PART_STRIDE + h] - Mg);
        Sg += pb[i * PART_STRIDE + 4 + h] * sc;
        Pg  = fmaf(pb[i * PART_STRIDE + 8 + t], sc, Pg);
    }
    out[(size_t)b * NROWS * HC + t] = Pg / Sg;
}

extern "C" void kernel_launch(void* const* d_in, const int* in_sizes, int n_in,
                              void* d_out, int out_size, void* d_ws, size_t ws_size,
                              hipStream_t stream)
{
    const float* x   = (const float*)d_in[0];
    const float* Wl  = (const float*)d_in[1];
    const float* bl  = (const float*)d_in[2];
    const float* Wr  = (const float*)d_in[3];
    const float* br  = (const float*)d_in[4];
    const float* att = (const float*)d_in[5];
    float* out = (float*)d_out;

    float* xl0  = (float*)d_ws;                // 32*128 f32
    float* part = xl0 + BATCH * 128;           // 32*32*136 f32

    gat_center<<<BATCH, 128, 0, stream>>>(x, Wl, bl, xl0);
    gat_main<<<BATCH * NBLK, 256, 0, stream>>>(x, Wr, br, att, xl0, out, part);
    gat_final<<<BATCH, 128, 0, stream>>>(part, out);
}